// Round 12
// baseline (34.140 us; speedup 1.0000x reference)
//
#include <hip/hip_runtime.h>
#include <math.h>

typedef unsigned long long u64;
typedef unsigned int u32;

#define N 4096
#define NW 64          // 64-bit words per 4096-bit row
#define ROWLEN 85
#define TS 1024        // col-tile size
#define NT 4           // number of col-tiles
#define NBLK 160       // working 64-row lower-triangle blocks: 64+48+32+16

// ---------------------------------------------------------------------------
// K1: decode — one wave per prediction row (4 rows/block). Writes the FINAL
//   fast-path output directly (keep == valid when suppression graph empty),
//   plus obox/skey/labels_i for K2; zeroes flag2 row; block 0 zeroes
//   rvalid/flagbits/anyedge/done_ctr (all rewritten every call -> replay-safe).
//   [proven r9/r11: absmax 0]
// ---------------------------------------------------------------------------
__global__ __launch_bounds__(256) void k_decode(const float* __restrict__ pred,
    float* __restrict__ out, int* __restrict__ labels_i, float* __restrict__ skey,
    float4* __restrict__ obox, u64* __restrict__ rvalid, u64* __restrict__ flagbits,
    u32* __restrict__ flag2, u32* __restrict__ anyedge, int* __restrict__ done_ctr) {
  if (blockIdx.x == 0) {
    int t = threadIdx.x;
    if (t < 64) rvalid[t] = 0ull;
    else if (t < 128) flagbits[t - 64] = 0ull;
    else if (t == 128) *anyedge = 0u;
    else if (t == 129) *done_ctr = 0;
  }
  int lane = threadIdx.x & 63;
  int r = (blockIdx.x << 2) + (threadIdx.x >> 6);
  const float* p = pred + r * ROWLEN;
  float conf = p[0];
  float c1 = p[1 + lane];
  float c2 = (lane < 16) ? p[65 + lane] : -INFINITY;
  float b0 = p[81], b1 = p[82], b2 = p[83], b3 = p[84];

  float m = fmaxf(c1, c2);
  for (int off = 32; off; off >>= 1) m = fmaxf(m, __shfl_xor(m, off));
  float s = expf(c1 - m) + expf(c2 - m);          // expf(-inf)=0 for lane>=16
  for (int off = 32; off; off >>= 1) s += __shfl_xor(s, off);

  float av = c1; int ai = lane;
  if (c2 > av) { av = c2; ai = 64 + lane; }
  for (int off = 32; off; off >>= 1) {
    float ov = __shfl_xor(av, off); int oi = __shfl_xor(ai, off);
    if (ov > av || (ov == av && oi < ai)) { av = ov; ai = oi; }
  }

  if (lane == 0) {
    float sig = 1.0f / (1.0f + expf(-conf));
    float score = sig * (1.0f / s);               // sig * softmax_max (ref op order)
    float gx = (float)(r >> 6), gy = (float)(r & 63);
    float cx = (1.0f / (1.0f + expf(-b0)) + gx) * 32.0f;
    float cy = (1.0f / (1.0f + expf(-b1)) + gy) * 32.0f;
    float wx = expf(b2), wy = expf(b3);
    const float inv = 1.0f / 2048.0f;
    float x1 = fminf(fmaxf((cx - wx) * inv, 0.0f), 1.0f);
    float y1 = fminf(fmaxf((cy - wy) * inv, 0.0f), 1.0f);
    float x2 = fminf(fmaxf((cx + wx) * inv, 0.0f), 1.0f);
    float y2 = fminf(fmaxf((cy + wy) * inv, 0.0f), 1.0f);
    float vm = (score > 0.01f) ? 1.0f : 0.0f;     // fast-path keep == valid
    out[r*5+0] = x1 * vm; out[r*5+1] = y1 * vm;
    out[r*5+2] = x2 * vm; out[r*5+3] = y2 * vm;
    out[r*5+4] = score * vm;
    out[N*5 + r] = (float)ai;                     // labels output (unmasked)
    out[N*5 + N + r] = vm;                        // keep output
    labels_i[r] = ai;
    skey[r] = (score > 0.01f) ? score : -1.0f;    // key: invalids tie below valids
    obox[r] = make_float4(x1, y1, x2, y2);
    flag2[r] = 0u;
  }
}

// ---------------------------------------------------------------------------
// K2: edge-DETECT only. 160 blocks, 64 rows each (4 row-groups reuse one
//   staged tile -> 4x staging amortization vs r11); staging trimmed to the
//   j<i prefix actually consumed. Last block to finish (threadfence election,
//   increment-and-exit, deadlock-free): anyedge==0 -> return (decode output
//   already final). anyedge!=0 -> single-block correctness-only fallback.
// ---------------------------------------------------------------------------
__global__ __launch_bounds__(256) void k_edge(const float* __restrict__ skey,
    const int* __restrict__ labels_i, const float4* __restrict__ obox,
    float* __restrict__ out, int* __restrict__ rank_g, float4* __restrict__ rbox,
    int* __restrict__ rlabel, u64* __restrict__ rvalid, u64* __restrict__ flagbits,
    u32* __restrict__ flag2, u64* __restrict__ mat, u64* __restrict__ diag,
    u32* anyedge, int* __restrict__ done_ctr) {
  __shared__ u64 shm[4096];          // 32KB multi-role
  __shared__ u64 skept[64];
  __shared__ int amLast, snv;
  float4* sbox  = (float4*)shm;                    // [1024]
  int*    slab  = (int*)(shm + 2048);              // [1024]
  float*  sarea = (float*)(shm + 2560);            // [1024]

  int tid = threadIdx.x, lane = tid & 63, w = tid >> 6;
  // linear bid -> (t, rcBig) over 64-row lower-triangle working set:
  //   t=0: rcBig 0..63 | t=1: 16..63 | t=2: 32..63 | t=3: 48..63
  int bid = blockIdx.x;
  int t, rcBig;
  if (bid < 64)       { t = 0; rcBig = bid; }
  else if (bid < 112) { t = 1; rcBig = bid - 64 + 16; }
  else if (bid < 144) { t = 2; rcBig = bid - 112 + 32; }
  else                { t = 3; rcBig = bid - 144 + 48; }
  int base = t << 10;
  int rtop = (rcBig << 6) + 63;                    // top row of this block

  {
    // stage only the prefix of cols that any row-group will read:
    // cols [base, base + kmax), kmax = roundup(rtop+3-base+1, 64) capped at TS
    int needed = rtop + 3 - base + 1;
    int kmax = (needed + 63) & ~63;
    kmax = kmax > TS ? TS : kmax;
    for (int k = tid; k < kmax; k += 256) {
      float4 bb = obox[base + k];
      sbox[k] = bb;
      slab[k] = (skey[base + k] > 0.0f) ? labels_i[base + k] : -1;
      sarea[k] = (bb.w - bb.y) * (bb.z - bb.x);
    }
    __syncthreads();
    bool hit = false;
    for (int q4 = 0; q4 < 4; ++q4) {               // 4 row-groups reuse the tile
      int r0 = (rcBig << 6) + (q4 << 4) + (w << 2);
      float4 br[4]; float ar[4]; int lr[4];
      #pragma unroll
      for (int q = 0; q < 4; ++q) {
        int rq = r0 + q;
        br[q] = obox[rq];
        ar[q] = (br[q].w - br[q].y) * (br[q].z - br[q].x);
        lr[q] = (skey[rq] > 0.0f) ? labels_i[rq] : -2;
      }
      int wcap = ((r0 + 3) - base) >> 6;           // words holding j<i cols
      wcap = wcap < 0 ? 0 : (wcap > 15 ? 15 : wcap);
      for (int wd = 0; wd <= wcap; ++wd) {
        int sl2 = (wd << 6) + lane;
        float4 bs = sbox[sl2];
        int ls = slab[sl2];
        float as_ = sarea[sl2];
        #pragma unroll
        for (int q = 0; q < 4; ++q) {
          float xx1 = fmaxf(br[q].x, bs.x);
          float yy1 = fmaxf(br[q].y, bs.y);
          float xx2 = fminf(br[q].z, bs.z);
          float yy2 = fminf(br[q].w, bs.w);
          float inter = fmaxf(xx2 - xx1, 0.0f) * fmaxf(yy2 - yy1, 0.0f);
          // IoU>0.5 <=> 3*inter > ar+as (uni==0 -> ref NaN>0.5=false, ours false)
          hit |= (ls == lr[q]) && (3.0f * inter > ar[q] + as_) && (base + sl2 < r0 + q);
        }
      }
    }
    u64 bal = __ballot(hit);
    if (lane == 0 && bal) atomicOr(anyedge, 1u);
  }

  // ---- last-block election (threadfence-reduction, proven r5-r9/r11) ----
  __syncthreads();
  if (tid == 0) {
    __threadfence();
    int prev = atomicAdd(done_ctr, 1);
    amLast = (prev == NBLK - 1);
  }
  __syncthreads();
  if (!amLast) return;
  __threadfence();
  if (atomicAdd(anyedge, 0u) == 0u) return;       // fast path: output already final

  // ============== slow path: single block, correctness-only ==============
  // 1) rank + permute-scatter
  float* skeyL = (float*)shm;
  __syncthreads();
  for (int k = tid; k < 4096; k += 256) skeyL[k] = skey[k];
  __syncthreads();
  for (int ii = 0; ii < 16; ++ii) {
    int i = (ii << 8) + tid;
    float ki = skeyL[i];
    int cnt = 0;
    for (int j = 0; j < 4096; ++j) {
      float kj = skeyL[j];
      cnt += (kj > ki || (kj == ki && j < i)) ? 1 : 0;   // stable descending rank
    }
    rank_g[i] = cnt;
    rbox[cnt] = obox[i];
    rlabel[cnt] = labels_i[i];
    if (ki > 0.0f)
      atomicOr((unsigned long long*)&rvalid[cnt >> 6], 1ull << (cnt & 63));
  }
  __syncthreads();
  __threadfence();
  if (tid < 64) {                    // nvalid = popcount(rvalid)
    int pc = __popcll(rvalid[tid]);
    for (int off = 32; off; off >>= 1) pc += __shfl_xor(pc, off);
    if (tid == 0) snv = pc;
  }
  __syncthreads();
  int nvalid = snv;

  // 2) suppression bit-matrix (valid-pruned, sparse segments + flag2 guard)
  for (int tt = 0; tt < NT; ++tt) {
    int cb = tt << 10;
    __syncthreads();
    for (int k = tid; k < TS; k += 256) {
      float4 bb = rbox[cb + k];
      sbox[k] = bb;
      slab[k] = (cb + k < nvalid) ? rlabel[cb + k] : -1;
      sarea[k] = (bb.w - bb.y) * (bb.z - bb.x);
    }
    __syncthreads();
    int wmax = (nvalid - cb + 63) >> 6;
    wmax = wmax < 0 ? 0 : (wmax > 16 ? 16 : wmax);
    for (int rc2 = 0; rc2 < 256; ++rc2) {
      int r0 = (rc2 << 4) + (w << 2);
      float4 br[4]; float ar[4]; int lr[4]; u64 myw[4];
      #pragma unroll
      for (int q = 0; q < 4; ++q) {
        br[q] = rbox[r0 + q];
        ar[q] = (br[q].w - br[q].y) * (br[q].z - br[q].x);
        lr[q] = (r0 + q < nvalid) ? rlabel[r0 + q] : -2;
        myw[q] = 0ull;
      }
      if (r0 < nvalid) {
        for (int wd = 0; wd < wmax; ++wd) {
          int sl2 = (wd << 6) + lane;
          float4 bs = sbox[sl2];
          int ls = slab[sl2];
          float as_ = sarea[sl2];
          #pragma unroll
          for (int q = 0; q < 4; ++q) {
            float xx1 = fmaxf(br[q].x, bs.x);
            float yy1 = fmaxf(br[q].y, bs.y);
            float xx2 = fminf(br[q].z, bs.z);
            float yy2 = fminf(br[q].w, bs.w);
            float inter = fmaxf(xx2 - xx1, 0.0f) * fmaxf(yy2 - yy1, 0.0f);
            bool sup = (ls == lr[q]) && (3.0f * inter > ar[q] + as_);
            u64 bal = __ballot(sup);
            if (lane == wd) myw[q] = bal;          // lane wd keeps word wd
          }
        }
      }
      #pragma unroll
      for (int q = 0; q < 4; ++q) {
        int r = r0 + q;
        int ws_ = (r >> 6) - (tt << 4);
        if (ws_ >= 0 && ws_ < 16 && lane == ws_)
          myw[q] &= ~(1ull << (r & 63));           // clear self bit (sg != r)
        u64 segnz = __ballot((lane < 16) && (myw[q] != 0ull));
        if ((lane < 16) && segnz)
          mat[(size_t)r * NW + (tt << 4) + lane] = myw[q];
        if (ws_ >= 0 && ws_ < 16 && lane == ws_) diag[r] = myw[q];
        if (lane == 0 && segnz) {
          atomicOr(&flag2[r], 1u << tt);
          atomicOr((unsigned long long*)&flagbits[r >> 6], 1ull << (r & 63));
        }
      }
    }
  }

  // 3) greedy scan (proven r7 logic)
  __syncthreads();
  u64* sdiag = shm;
  for (int k = tid; k < 4096; k += 256) sdiag[k] = diag[k];
  __syncthreads();
  if (tid < 64) {
    u64 valid = rvalid[lane];
    u64 mflag = flagbits[lane];
    u64 supp = 0, kept = 0;
    u64 intra = sdiag[lane];
    for (int b = 0; b < 64; ++b) {
      u64 intra_next = (b < 63) ? sdiag[((b + 1) << 6) + lane] : 0ull;
      u64 flagw = __shfl(mflag, b);
      u64 sb = __shfl(supp, b);
      u64 vb = __shfl(valid, b);
      u64 act = vb & ~sb;
      u64 res = act;
      u64 anyintra = __ballot(intra != 0ull);
      if (anyintra & act) {
        u64 rem = act; res = 0;
        while (rem) {
          int pp = (int)__ffsll(rem) - 1;
          rem &= rem - 1;
          res |= 1ull << pp;
          rem &= ~__shfl(intra, pp);
        }
      }
      if (lane == b) kept = res;
      u64 need = res & flagw;
      while (need) {
        int pp = (int)__ffsll(need) - 1;
        need &= need - 1;
        int row = (b << 6) + pp;
        u32 f2 = flag2[row];
        if ((f2 >> (lane >> 4)) & 1)
          supp |= mat[(size_t)row * NW + lane];
      }
      intra = intra_next;
    }
    skept[lane] = kept;
  }
  __syncthreads();

  // 4) rewrite final output with the true keep mask
  for (int it = 0; it < 16; ++it) {
    int i = (it << 8) + tid;
    int r = rank_g[i];
    float kk = (float)((skept[r >> 6] >> (r & 63)) & 1ull);
    float4 bb = obox[i];
    float sc = skey[i];
    out[i*5+0] = bb.x * kk; out[i*5+1] = bb.y * kk;
    out[i*5+2] = bb.z * kk; out[i*5+3] = bb.w * kk;
    out[i*5+4] = (sc > 0.0f ? sc : 0.0f) * kk;
    out[N*5 + N + i] = kk;
  }
}

// ---------------------------------------------------------------------------
// ws layout (bytes):
//   0        mat       u64[4096*64]   2097152
//   2097152  rank_g    i32[4096]      16384
//   2113536  rbox      float4[4096]   65536
//   2179072  rlabel    i32[4096]      16384
//   2195456  diag      u64[4096]      32768
//   2228224  rvalid    u64[64]        512
//   2228736  flagbits  u64[64]        512
//   2229248  labels_i  i32[4096]      16384
//   2245632  skey      f32[4096]      16384
//   2262016  flag2     u32[4096]      16384
//   2278400  obox      float4[4096]   65536
//   2343936  anyedge   u32            512 (padded)
//   2344448  done_ctr  i32            512 (padded)
//   total 2344960 bytes
// ---------------------------------------------------------------------------
extern "C" void kernel_launch(void* const* d_in, const int* in_sizes, int n_in,
                              void* d_out, int out_size, void* d_ws, size_t ws_size,
                              hipStream_t stream) {
  const float* pred = (const float*)d_in[0];
  float* out = (float*)d_out;
  char* ws = (char*)d_ws;
  u64*    mat      = (u64*)(ws);
  int*    rank_g   = (int*)(ws + 2097152);
  float4* rbox     = (float4*)(ws + 2113536);
  int*    rlabel   = (int*)(ws + 2179072);
  u64*    diag     = (u64*)(ws + 2195456);
  u64*    rvalid   = (u64*)(ws + 2228224);
  u64*    flagbits = (u64*)(ws + 2228736);
  int*    labels_i = (int*)(ws + 2229248);
  float*  skey     = (float*)(ws + 2245632);
  u32*    flag2    = (u32*)(ws + 2262016);
  float4* obox     = (float4*)(ws + 2278400);
  u32*    anyedge  = (u32*)(ws + 2343936);
  int*    done_ctr = (int*)(ws + 2344448);

  k_decode<<<1024, 256, 0, stream>>>(pred, out, labels_i, skey, obox,
                                     rvalid, flagbits, flag2, anyedge, done_ctr);
  k_edge  <<<NBLK, 256, 0, stream>>>(skey, labels_i, obox, out, rank_g, rbox,
                                     rlabel, rvalid, flagbits, flag2, mat, diag,
                                     anyedge, done_ctr);
}

// Round 13
// 25.954 us; speedup vs baseline: 1.3154x; 1.3154x over previous
//
#include <hip/hip_runtime.h>
#include <math.h>

typedef unsigned long long u64;
typedef unsigned int u32;

#define N 4096
#define NW 64          // 64-bit words per 4096-bit row
#define ROWLEN 85
#define TS 1024        // col-tile size
#define NT 4           // number of col-tiles
#define NEDGE 640      // working lower-triangle blocks: 256+192+128+64

// ---------------------------------------------------------------------------
// K1: decode — one wave per prediction row (4 rows/block). Writes the FINAL
//   fast-path output directly (keep == valid when suppression graph empty),
//   plus obox/skey/labels_i for K2; zeroes flag2 row; block 0 zeroes
//   rvalid/flagbits/anyedge/done_ctr (all rewritten every call -> replay-safe).
//   [proven r9/r11: absmax 0; r11 total 26.4 us]
// ---------------------------------------------------------------------------
__global__ __launch_bounds__(256) void k_decode(const float* __restrict__ pred,
    float* __restrict__ out, int* __restrict__ labels_i, float* __restrict__ skey,
    float4* __restrict__ obox, u64* __restrict__ rvalid, u64* __restrict__ flagbits,
    u32* __restrict__ flag2, u32* __restrict__ anyedge, int* __restrict__ done_ctr) {
  if (blockIdx.x == 0) {
    int t = threadIdx.x;
    if (t < 64) rvalid[t] = 0ull;
    else if (t < 128) flagbits[t - 64] = 0ull;
    else if (t == 128) *anyedge = 0u;
    else if (t == 129) *done_ctr = 0;
  }
  int lane = threadIdx.x & 63;
  int r = (blockIdx.x << 2) + (threadIdx.x >> 6);
  const float* p = pred + r * ROWLEN;
  float conf = p[0];
  float c1 = p[1 + lane];
  float c2 = (lane < 16) ? p[65 + lane] : -INFINITY;
  float b0 = p[81], b1 = p[82], b2 = p[83], b3 = p[84];

  float m = fmaxf(c1, c2);
  for (int off = 32; off; off >>= 1) m = fmaxf(m, __shfl_xor(m, off));
  float s = expf(c1 - m) + expf(c2 - m);          // expf(-inf)=0 for lane>=16
  for (int off = 32; off; off >>= 1) s += __shfl_xor(s, off);

  float av = c1; int ai = lane;
  if (c2 > av) { av = c2; ai = 64 + lane; }
  for (int off = 32; off; off >>= 1) {
    float ov = __shfl_xor(av, off); int oi = __shfl_xor(ai, off);
    if (ov > av || (ov == av && oi < ai)) { av = ov; ai = oi; }
  }

  if (lane == 0) {
    float sig = 1.0f / (1.0f + expf(-conf));
    float score = sig * (1.0f / s);               // sig * softmax_max (ref op order)
    float gx = (float)(r >> 6), gy = (float)(r & 63);
    float cx = (1.0f / (1.0f + expf(-b0)) + gx) * 32.0f;
    float cy = (1.0f / (1.0f + expf(-b1)) + gy) * 32.0f;
    float wx = expf(b2), wy = expf(b3);
    const float inv = 1.0f / 2048.0f;
    float x1 = fminf(fmaxf((cx - wx) * inv, 0.0f), 1.0f);
    float y1 = fminf(fmaxf((cy - wy) * inv, 0.0f), 1.0f);
    float x2 = fminf(fmaxf((cx + wx) * inv, 0.0f), 1.0f);
    float y2 = fminf(fmaxf((cy + wy) * inv, 0.0f), 1.0f);
    float vm = (score > 0.01f) ? 1.0f : 0.0f;     // fast-path keep == valid
    out[r*5+0] = x1 * vm; out[r*5+1] = y1 * vm;
    out[r*5+2] = x2 * vm; out[r*5+3] = y2 * vm;
    out[r*5+4] = score * vm;
    out[N*5 + r] = (float)ai;                     // labels output (unmasked)
    out[N*5 + N + r] = vm;                        // keep output
    labels_i[r] = ai;
    skey[r] = (score > 0.01f) ? score : -1.0f;    // key: invalids tie below valids
    obox[r] = make_float4(x1, y1, x2, y2);
    flag2[r] = 0u;
  }
}

// ---------------------------------------------------------------------------
// K2: edge-DETECT only (original order; symmetric relation -> j<i pairs only;
//   ONLY the 640 working lower-triangle blocks are launched — r12 showed
//   fewer/fatter blocks lengthen the critical path and regress). Last block
//   to finish (threadfence election, increment-and-exit, deadlock-free):
//   anyedge==0 -> return (decode output already final). anyedge!=0 ->
//   single-block correctness-only fallback.
// ---------------------------------------------------------------------------
__global__ __launch_bounds__(256) void k_edge(const float* __restrict__ skey,
    const int* __restrict__ labels_i, const float4* __restrict__ obox,
    float* __restrict__ out, int* __restrict__ rank_g, float4* __restrict__ rbox,
    int* __restrict__ rlabel, u64* __restrict__ rvalid, u64* __restrict__ flagbits,
    u32* __restrict__ flag2, u64* __restrict__ mat, u64* __restrict__ diag,
    u32* anyedge, int* __restrict__ done_ctr) {
  __shared__ u64 shm[4096];          // 32KB multi-role
  __shared__ u64 skept[64];
  __shared__ int amLast, snv;
  float4* sbox  = (float4*)shm;                    // [1024]
  int*    slab  = (int*)(shm + 2048);              // [1024]
  float*  sarea = (float*)(shm + 2560);            // [1024]

  int tid = threadIdx.x, lane = tid & 63, w = tid >> 6;
  // linear bid -> (t, rc) over lower-triangle working set:
  //   t=0: rc 0..255 | t=1: rc 64..255 | t=2: rc 128..255 | t=3: rc 192..255
  int bid = blockIdx.x;
  int t, rc;
  if (bid < 256)      { t = 0; rc = bid; }
  else if (bid < 448) { t = 1; rc = bid - 256 + 64; }
  else if (bid < 576) { t = 2; rc = bid - 448 + 128; }
  else                { t = 3; rc = bid - 576 + 192; }
  int base = t << 10;

  {
    for (int k = tid; k < TS; k += 256) {
      float4 bb = obox[base + k];
      sbox[k] = bb;
      slab[k] = (skey[base + k] > 0.0f) ? labels_i[base + k] : -1;
      sarea[k] = (bb.w - bb.y) * (bb.z - bb.x);
    }
    __syncthreads();
    int r0 = (rc << 4) + (w << 2);   // 4 rows per wave
    float4 br[4]; float ar[4]; int lr[4];
    #pragma unroll
    for (int q = 0; q < 4; ++q) {
      int rq = r0 + q;
      br[q] = obox[rq];
      ar[q] = (br[q].w - br[q].y) * (br[q].z - br[q].x);
      lr[q] = (skey[rq] > 0.0f) ? labels_i[rq] : -2;
    }
    int wcap = ((r0 + 3) - base) >> 6;             // words holding j<i cols
    wcap = wcap < 0 ? 0 : (wcap > 15 ? 15 : wcap);
    bool hit = false;
    if (r0 + 3 >= base) {
      for (int wd = 0; wd <= wcap; ++wd) {
        int sl2 = (wd << 6) + lane;
        float4 bs = sbox[sl2];
        int ls = slab[sl2];
        float as_ = sarea[sl2];
        #pragma unroll
        for (int q = 0; q < 4; ++q) {
          float xx1 = fmaxf(br[q].x, bs.x);
          float yy1 = fmaxf(br[q].y, bs.y);
          float xx2 = fminf(br[q].z, bs.z);
          float yy2 = fminf(br[q].w, bs.w);
          float inter = fmaxf(xx2 - xx1, 0.0f) * fmaxf(yy2 - yy1, 0.0f);
          // IoU>0.5 <=> 3*inter > ar+as (uni==0 -> ref NaN>0.5=false, ours false)
          hit |= (ls == lr[q]) && (3.0f * inter > ar[q] + as_) && (base + sl2 < r0 + q);
        }
      }
    }
    u64 bal = __ballot(hit);
    if (lane == 0 && bal) atomicOr(anyedge, 1u);
  }

  // ---- last-block election (threadfence-reduction pattern, proven r5-r11) ----
  __syncthreads();
  if (tid == 0) {
    __threadfence();
    int prev = atomicAdd(done_ctr, 1);
    amLast = (prev == NEDGE - 1);
  }
  __syncthreads();
  if (!amLast) return;
  __threadfence();
  if (atomicAdd(anyedge, 0u) == 0u) return;       // fast path: output already final

  // ============== slow path: single block, correctness-only ==============
  // 1) rank + permute-scatter
  float* skeyL = (float*)shm;
  __syncthreads();
  for (int k = tid; k < 4096; k += 256) skeyL[k] = skey[k];
  __syncthreads();
  for (int ii = 0; ii < 16; ++ii) {
    int i = (ii << 8) + tid;
    float ki = skeyL[i];
    int cnt = 0;
    for (int j = 0; j < 4096; ++j) {
      float kj = skeyL[j];
      cnt += (kj > ki || (kj == ki && j < i)) ? 1 : 0;   // stable descending rank
    }
    rank_g[i] = cnt;
    rbox[cnt] = obox[i];
    rlabel[cnt] = labels_i[i];
    if (ki > 0.0f)
      atomicOr((unsigned long long*)&rvalid[cnt >> 6], 1ull << (cnt & 63));
  }
  __syncthreads();
  __threadfence();
  if (tid < 64) {                    // nvalid = popcount(rvalid)
    int pc = __popcll(rvalid[tid]);
    for (int off = 32; off; off >>= 1) pc += __shfl_xor(pc, off);
    if (tid == 0) snv = pc;
  }
  __syncthreads();
  int nvalid = snv;

  // 2) suppression bit-matrix (valid-pruned, sparse segments + flag2 guard)
  for (int tt = 0; tt < NT; ++tt) {
    int cb = tt << 10;
    __syncthreads();
    for (int k = tid; k < TS; k += 256) {
      float4 bb = rbox[cb + k];
      sbox[k] = bb;
      slab[k] = (cb + k < nvalid) ? rlabel[cb + k] : -1;
      sarea[k] = (bb.w - bb.y) * (bb.z - bb.x);
    }
    __syncthreads();
    int wmax = (nvalid - cb + 63) >> 6;
    wmax = wmax < 0 ? 0 : (wmax > 16 ? 16 : wmax);
    for (int rc2 = 0; rc2 < 256; ++rc2) {
      int r0 = (rc2 << 4) + (w << 2);
      float4 br[4]; float ar[4]; int lr[4]; u64 myw[4];
      #pragma unroll
      for (int q = 0; q < 4; ++q) {
        br[q] = rbox[r0 + q];
        ar[q] = (br[q].w - br[q].y) * (br[q].z - br[q].x);
        lr[q] = (r0 + q < nvalid) ? rlabel[r0 + q] : -2;
        myw[q] = 0ull;
      }
      if (r0 < nvalid) {
        for (int wd = 0; wd < wmax; ++wd) {
          int sl2 = (wd << 6) + lane;
          float4 bs = sbox[sl2];
          int ls = slab[sl2];
          float as_ = sarea[sl2];
          #pragma unroll
          for (int q = 0; q < 4; ++q) {
            float xx1 = fmaxf(br[q].x, bs.x);
            float yy1 = fmaxf(br[q].y, bs.y);
            float xx2 = fminf(br[q].z, bs.z);
            float yy2 = fminf(br[q].w, bs.w);
            float inter = fmaxf(xx2 - xx1, 0.0f) * fmaxf(yy2 - yy1, 0.0f);
            bool sup = (ls == lr[q]) && (3.0f * inter > ar[q] + as_);
            u64 bal = __ballot(sup);
            if (lane == wd) myw[q] = bal;          // lane wd keeps word wd
          }
        }
      }
      #pragma unroll
      for (int q = 0; q < 4; ++q) {
        int r = r0 + q;
        int ws_ = (r >> 6) - (tt << 4);
        if (ws_ >= 0 && ws_ < 16 && lane == ws_)
          myw[q] &= ~(1ull << (r & 63));           // clear self bit (sg != r)
        u64 segnz = __ballot((lane < 16) && (myw[q] != 0ull));
        if ((lane < 16) && segnz)
          mat[(size_t)r * NW + (tt << 4) + lane] = myw[q];
        if (ws_ >= 0 && ws_ < 16 && lane == ws_) diag[r] = myw[q];
        if (lane == 0 && segnz) {
          atomicOr(&flag2[r], 1u << tt);
          atomicOr((unsigned long long*)&flagbits[r >> 6], 1ull << (r & 63));
        }
      }
    }
  }

  // 3) greedy scan (proven r7 logic)
  __syncthreads();
  u64* sdiag = shm;
  for (int k = tid; k < 4096; k += 256) sdiag[k] = diag[k];
  __syncthreads();
  if (tid < 64) {
    u64 valid = rvalid[lane];
    u64 mflag = flagbits[lane];
    u64 supp = 0, kept = 0;
    u64 intra = sdiag[lane];
    for (int b = 0; b < 64; ++b) {
      u64 intra_next = (b < 63) ? sdiag[((b + 1) << 6) + lane] : 0ull;
      u64 flagw = __shfl(mflag, b);
      u64 sb = __shfl(supp, b);
      u64 vb = __shfl(valid, b);
      u64 act = vb & ~sb;
      u64 res = act;
      u64 anyintra = __ballot(intra != 0ull);
      if (anyintra & act) {
        u64 rem = act; res = 0;
        while (rem) {
          int pp = (int)__ffsll(rem) - 1;
          rem &= rem - 1;
          res |= 1ull << pp;
          rem &= ~__shfl(intra, pp);
        }
      }
      if (lane == b) kept = res;
      u64 need = res & flagw;
      while (need) {
        int pp = (int)__ffsll(need) - 1;
        need &= need - 1;
        int row = (b << 6) + pp;
        u32 f2 = flag2[row];
        if ((f2 >> (lane >> 4)) & 1)
          supp |= mat[(size_t)row * NW + lane];
      }
      intra = intra_next;
    }
    skept[lane] = kept;
  }
  __syncthreads();

  // 4) rewrite final output with the true keep mask
  for (int it = 0; it < 16; ++it) {
    int i = (it << 8) + tid;
    int r = rank_g[i];
    float kk = (float)((skept[r >> 6] >> (r & 63)) & 1ull);
    float4 bb = obox[i];
    float sc = skey[i];
    out[i*5+0] = bb.x * kk; out[i*5+1] = bb.y * kk;
    out[i*5+2] = bb.z * kk; out[i*5+3] = bb.w * kk;
    out[i*5+4] = (sc > 0.0f ? sc : 0.0f) * kk;
    out[N*5 + N + i] = kk;
  }
}

// ---------------------------------------------------------------------------
// ws layout (bytes):
//   0        mat       u64[4096*64]   2097152
//   2097152  rank_g    i32[4096]      16384
//   2113536  rbox      float4[4096]   65536
//   2179072  rlabel    i32[4096]      16384
//   2195456  diag      u64[4096]      32768
//   2228224  rvalid    u64[64]        512
//   2228736  flagbits  u64[64]        512
//   2229248  labels_i  i32[4096]      16384
//   2245632  skey      f32[4096]      16384
//   2262016  flag2     u32[4096]      16384
//   2278400  obox      float4[4096]   65536
//   2343936  anyedge   u32            512 (padded)
//   2344448  done_ctr  i32            512 (padded)
//   total 2344960 bytes
// ---------------------------------------------------------------------------
extern "C" void kernel_launch(void* const* d_in, const int* in_sizes, int n_in,
                              void* d_out, int out_size, void* d_ws, size_t ws_size,
                              hipStream_t stream) {
  const float* pred = (const float*)d_in[0];
  float* out = (float*)d_out;
  char* ws = (char*)d_ws;
  u64*    mat      = (u64*)(ws);
  int*    rank_g   = (int*)(ws + 2097152);
  float4* rbox     = (float4*)(ws + 2113536);
  int*    rlabel   = (int*)(ws + 2179072);
  u64*    diag     = (u64*)(ws + 2195456);
  u64*    rvalid   = (u64*)(ws + 2228224);
  u64*    flagbits = (u64*)(ws + 2228736);
  int*    labels_i = (int*)(ws + 2229248);
  float*  skey     = (float*)(ws + 2245632);
  u32*    flag2    = (u32*)(ws + 2262016);
  float4* obox     = (float4*)(ws + 2278400);
  u32*    anyedge  = (u32*)(ws + 2343936);
  int*    done_ctr = (int*)(ws + 2344448);

  k_decode<<<1024, 256, 0, stream>>>(pred, out, labels_i, skey, obox,
                                     rvalid, flagbits, flag2, anyedge, done_ctr);
  k_edge  <<<NEDGE, 256, 0, stream>>>(skey, labels_i, obox, out, rank_g, rbox,
                                      rlabel, rvalid, flagbits, flag2, mat, diag,
                                      anyedge, done_ctr);
}